// Round 1
// baseline (1172.735 us; speedup 1.0000x reference)
//
#include <hip/hip_runtime.h>

// Problem constants (from reference)
#define N_NODES 25000
#define N_EDGES 200000
// MUL=16, NUM_RADIAL=8, HIDDEN=64, WNUMEL=1024
// PATH_ALPHA = 1/sqrt(32), INV_SQRT3 = 1/sqrt(3)

constexpr int TILE = 64;                       // edges per LDS tile
constexpr int TILES = N_EDGES / TILE;          // 3125
constexpr int BLOCKS_PER_PROG = 625;
constexpr int TILES_PER_BLOCK = TILES / BLOCKS_PER_PROG; // 5

__device__ __forceinline__ float reduce16(float v) {
    // butterfly over the 16-lane u-group (u = lane & 15)
    v += __shfl_xor(v, 1, 64);
    v += __shfl_xor(v, 2, 64);
    v += __shfl_xor(v, 4, 64);
    v += __shfl_xor(v, 8, 64);
    return v;
}

// Kernel 1: out = sc (self-connection). Fully overwrites d_out.
__global__ __launch_bounds__(256) void sc_kernel(const float* __restrict__ x,
                                                 const float* __restrict__ L0,
                                                 const float* __restrict__ L1,
                                                 float* __restrict__ out) {
    int idx = blockIdx.x * 256 + threadIdx.x;
    if (idx >= N_NODES * 64) return;
    int n = idx >> 6, j = idx & 63;
    const float* xr = x + n * 64;
    float s = 0.f;
    if (j < 16) {
        int v = j;
        #pragma unroll
        for (int u = 0; u < 16; ++u) s = fmaf(xr[u], L0[u * 16 + v], s);
    } else {
        int v = (j - 16) / 3, k = (j - 16) % 3;
        #pragma unroll
        for (int u = 0; u < 16; ++u) s = fmaf(xr[16 + u * 3 + k], L1[u * 16 + v], s);
    }
    out[idx] = 0.25f * s;  // 1/sqrt(MUL)
}

// Kernel 2: per-edge message passing, atomically accumulated into out.
// blockIdx & 3 = "program" = which 16x16 block of w (256-col chunk of W2).
// Thread t owns W2 column prog*256 + (t&15)*16 + (t>>4): u = t&15 (reduced
// in-wave over 16 contiguous lanes), v = t>>4 (output index).
__global__ __launch_bounds__(256) void edge_kernel(
    const float* __restrict__ x, const float* __restrict__ edge_attr,
    const float* __restrict__ edge_length, const int* __restrict__ edge_src,
    const int* __restrict__ edge_dst, const float* __restrict__ W1,
    const float* __restrict__ W2, float* __restrict__ out) {

    const int t = threadIdx.x;
    const int prog = blockIdx.x & 3;
    const int bid = blockIdx.x >> 2;
    const int u = t & 15;
    const int v = t >> 4;
    const int lane = t & 63;
    const int grp = t >> 6;   // wave id within block

    __shared__ float lds_xj[TILE][64];   // gathered x[src] rows
    __shared__ float lds_h[TILE][64];    // silu MLP hidden
    __shared__ float lds_rad[TILE][8];
    __shared__ float lds_sh[TILE][4];
    __shared__ int   lds_dst[TILE];

    // Fold all static scales into the register-resident W2 column:
    // (1/sqrt(HIDDEN)) * PATH_ALPHA, and INV_SQRT3 for program 1.
    float scale = 0.125f * 0.17677669529663687f;
    if (prog == 1) scale *= 0.5773502691896258f;
    const int col = prog * 256 + u * 16 + v;
    float w2r[64];
    #pragma unroll
    for (int c = 0; c < 64; ++c) w2r[c] = W2[c * 1024 + col] * scale;

    // W1 column for the h-compute pass (c = t & 63 is fixed per thread)
    const int cA = t & 63;
    float w1r[8];
    #pragma unroll
    for (int r = 0; r < 8; ++r) w1r[r] = W1[r * 64 + cA];

    for (int tl = 0; tl < TILES_PER_BLOCK; ++tl) {
        const int e0 = (bid + tl * BLOCKS_PER_PROG) * TILE;
        __syncthreads();  // protect LDS from previous tile's readers

        // --- stage per-edge scalars + radial basis (wave 0) ---
        if (t < TILE) {
            const int e = e0 + t;
            lds_dst[t] = edge_dst[e];
            const float len = edge_length[e];
            #pragma unroll
            for (int r = 0; r < 8; ++r) {
                float d = len - (5.0f / 7.0f) * (float)r;
                lds_rad[t][r] = __expf(-0.5f * d * d);
            }
            const float4 ea = *(const float4*)(edge_attr + 4 * e);
            lds_sh[t][0] = ea.x; lds_sh[t][1] = ea.y;
            lds_sh[t][2] = ea.z; lds_sh[t][3] = ea.w;
        }
        // --- gather x[src] rows (64B/lane, coalesced 256B rows) ---
        #pragma unroll
        for (int i = 0; i < 16; ++i) {
            const int e = i * 4 + grp;
            const int src = edge_src[e0 + e];  // wave-uniform -> scalar load
            lds_xj[e][lane] = x[src * 64 + lane];
        }
        __syncthreads();

        // --- h = silu(radial @ W1 / sqrt(8)) ---
        #pragma unroll
        for (int m = 0; m < 16; ++m) {
            const int e = m * 4 + grp;  // wave-uniform -> broadcast LDS reads
            float s = 0.f;
            #pragma unroll
            for (int r = 0; r < 8; ++r) s = fmaf(lds_rad[e][r], w1r[r], s);
            s *= 0.3535533905932738f;
            lds_h[e][cA] = s / (1.f + __expf(-s));
        }
        __syncthreads();

        // --- per edge: w column dot + contraction + scatter ---
        for (int e = 0; e < TILE; ++e) {
            const float4* h4 = (const float4*)lds_h[e];
            float acc0 = 0.f, acc1 = 0.f, acc2 = 0.f, acc3 = 0.f;
            #pragma unroll
            for (int c4 = 0; c4 < 4; ++c4) {
                float4 p0 = h4[c4];
                float4 p1 = h4[4 + c4];
                float4 p2 = h4[8 + c4];
                float4 p3 = h4[12 + c4];
                acc0 = fmaf(p0.x, w2r[c4 * 4 + 0], acc0);
                acc0 = fmaf(p0.y, w2r[c4 * 4 + 1], acc0);
                acc0 = fmaf(p0.z, w2r[c4 * 4 + 2], acc0);
                acc0 = fmaf(p0.w, w2r[c4 * 4 + 3], acc0);
                acc1 = fmaf(p1.x, w2r[16 + c4 * 4 + 0], acc1);
                acc1 = fmaf(p1.y, w2r[16 + c4 * 4 + 1], acc1);
                acc1 = fmaf(p1.z, w2r[16 + c4 * 4 + 2], acc1);
                acc1 = fmaf(p1.w, w2r[16 + c4 * 4 + 3], acc1);
                acc2 = fmaf(p2.x, w2r[32 + c4 * 4 + 0], acc2);
                acc2 = fmaf(p2.y, w2r[32 + c4 * 4 + 1], acc2);
                acc2 = fmaf(p2.z, w2r[32 + c4 * 4 + 2], acc2);
                acc2 = fmaf(p2.w, w2r[32 + c4 * 4 + 3], acc2);
                acc3 = fmaf(p3.x, w2r[48 + c4 * 4 + 0], acc3);
                acc3 = fmaf(p3.y, w2r[48 + c4 * 4 + 1], acc3);
                acc3 = fmaf(p3.z, w2r[48 + c4 * 4 + 2], acc3);
                acc3 = fmaf(p3.w, w2r[48 + c4 * 4 + 3], acc3);
            }
            const float w = (acc0 + acc1) + (acc2 + acc3); // w[e][prog][u][v] (pre-scaled)
            const int dst = lds_dst[e];
            float* op = out + dst * 64;

            if (prog == 0) {
                // m0 += (xj0*sh0) . w0
                float val = reduce16(w * lds_xj[e][u] * lds_sh[e][0]);
                if (u == 0) atomicAdd(op + v, val);
            } else if (prog == 1) {
                // m0 += INV_SQRT3 * (sum_k xj1[u,k]*sh1[k]) . w1  (INV_SQRT3 folded)
                float val = w * fmaf(lds_xj[e][16 + 3 * u], lds_sh[e][1],
                             fmaf(lds_xj[e][17 + 3 * u], lds_sh[e][2],
                                  lds_xj[e][18 + 3 * u] * lds_sh[e][3]));
                val = reduce16(val);
                if (u == 0) atomicAdd(op + v, val);
            } else if (prog == 2) {
                // m1[v,k] += sh1[k] * (xj0 . w2)[v]
                float val = reduce16(w * lds_xj[e][u]);
                if (u < 3) atomicAdd(op + 16 + v * 3 + u, val * lds_sh[e][1 + u]);
            } else {
                // m1[v,k] += sh0 * (xj1[:,k] . w3)[v]
                float r0 = reduce16(w * lds_xj[e][16 + 3 * u]);
                float r1 = reduce16(w * lds_xj[e][17 + 3 * u]);
                float r2 = reduce16(w * lds_xj[e][18 + 3 * u]);
                if (u < 3) {
                    float rv = (u == 0) ? r0 : ((u == 1) ? r1 : r2);
                    atomicAdd(op + 16 + v * 3 + u, rv * lds_sh[e][0]);
                }
            }
        }
    }
}

extern "C" void kernel_launch(void* const* d_in, const int* in_sizes, int n_in,
                              void* d_out, int out_size, void* d_ws, size_t ws_size,
                              hipStream_t stream) {
    const float* x           = (const float*)d_in[0];
    const float* edge_attr   = (const float*)d_in[1];
    const float* edge_length = (const float*)d_in[2];
    const int*   edge_src    = (const int*)d_in[3];
    const int*   edge_dst    = (const int*)d_in[4];
    const float* W1          = (const float*)d_in[5];
    const float* W2          = (const float*)d_in[6];
    const float* L0          = (const float*)d_in[7];
    const float* L1          = (const float*)d_in[8];
    float* out = (float*)d_out;

    sc_kernel<<<(N_NODES * 64 + 255) / 256, 256, 0, stream>>>(x, L0, L1, out);
    edge_kernel<<<4 * BLOCKS_PER_PROG, 256, 0, stream>>>(
        x, edge_attr, edge_length, edge_src, edge_dst, W1, W2, out);
}

// Round 4
// 330.043 us; speedup vs baseline: 3.5533x; 3.5533x over previous
//
#include <hip/hip_runtime.h>

// Problem constants
#define N_NODES 25000
#define N_EDGES 200000
// MUL=16, NUM_RADIAL=8, HIDDEN=64, WNUMEL=1024
// PATH_ALPHA=1/sqrt(32), INV_SQRT3=1/sqrt(3), scales folded into B-fragments.

constexpr int ET = 16;     // edges per tile
constexpr int NT = 25;     // tiles per block
constexpr int NBLK = 500;  // 500*25*16 = 200000 edges exactly

typedef __attribute__((ext_vector_type(8))) _Float16 half8;  // 8 f16 (4 VGPR)
typedef __attribute__((ext_vector_type(4))) float float4v;   // 4 fp32

// ---------------- self-connection (round-1 verified version) ----------------
__global__ __launch_bounds__(256) void sc_kernel(const float* __restrict__ x,
                                                 const float* __restrict__ L0,
                                                 const float* __restrict__ L1,
                                                 float* __restrict__ out) {
    int idx = blockIdx.x * 256 + threadIdx.x;
    if (idx >= N_NODES * 64) return;
    int n = idx >> 6, j = idx & 63;
    const float* xr = x + n * 64;
    float s = 0.f;
    if (j < 16) {
        int v = j;
        #pragma unroll
        for (int u = 0; u < 16; ++u) s = fmaf(xr[u], L0[u * 16 + v], s);
    } else {
        int v = (j - 16) / 3, k = (j - 16) % 3;
        #pragma unroll
        for (int u = 0; u < 16; ++u) s = fmaf(xr[16 + u * 3 + k], L1[u * 16 + v], s);
    }
    out[idx] = 0.25f * s;  // 1/sqrt(MUL)
}

// ---------------- edge kernel: f16 MFMA GEMM + fused contraction ----------------
// Differential vs round 3: (1) h staged fp32 in LDS, f16 hi/lo built in regs;
// (2) no cross-wave exchange -- each prog atomics its own term; (3) aligned LDS.
__global__ __launch_bounds__(256, 2) void edge_kernel(
    const float* __restrict__ x, const float* __restrict__ edge_attr,
    const float* __restrict__ edge_length, const int* __restrict__ edge_src,
    const int* __restrict__ edge_dst, const float* __restrict__ W1,
    const float* __restrict__ W2, float* __restrict__ out) {

    const int t = threadIdx.x;
    const int prog = t >> 6;          // wave id == which 16x16-block family of w
    const int qm = t & 15;            // MFMA n / v / m index
    const int quad = (t >> 4) & 3;    // lane quad

    __shared__ __attribute__((aligned(16))) float lds_h[16 * 72];   // fp32 h, row stride 72
    __shared__ __attribute__((aligned(16))) float lds_xj[16 * 68];  // gathered x[src], stride 68
    __shared__ __attribute__((aligned(16))) float lds_b1[16 * 68];  // b1[e][u]=sum_k xj1[u,k]sh1[k]
    __shared__ __attribute__((aligned(16))) float lds_xt[48 * 20];  // xj1 transposed: row e*3+k, [u]
    __shared__ __attribute__((aligned(16))) float lds_w1t[64 * 8];  // W1 transposed [c][r]
    __shared__ __attribute__((aligned(16))) float lds_sh[16 * 4];
    __shared__ __attribute__((aligned(16))) float lds_len[16];
    __shared__ __attribute__((aligned(16))) int   lds_dst[16];

    // ---- persistent B fragments: W2 block `prog`, pre-scaled, f16 ----
    // B-frag layout (16x16x32): lane holds B[k = kf*32 + quad*8 + j][n = qm]
    half8 bfr[16][2];
    {
        float scale = 0.0220970869f;                  // (1/sqrt(64)) * (1/sqrt(32))
        if (prog == 1) scale *= 0.5773502692f;        // INV_SQRT3 folded
        const int kr = quad * 8;
        const int col0 = prog * 256 + qm;
        #pragma unroll
        for (int u = 0; u < 16; ++u) {
            #pragma unroll
            for (int kf = 0; kf < 2; ++kf) {
                half8 f;
                #pragma unroll
                for (int j = 0; j < 8; ++j) {
                    const int k = kf * 32 + kr + j;
                    f[j] = (_Float16)(W2[k * 1024 + col0 + u * 16] * scale);
                }
                bfr[u][kf] = f;
            }
        }
    }
    // W1 -> LDS transposed [c][r]
    for (int i = t; i < 512; i += 256) {
        const int r = i >> 6, c = i & 63;
        lds_w1t[c * 8 + r] = W1[i];
    }

    for (int tl = 0; tl < NT; ++tl) {
        const int e0 = (blockIdx.x * NT + tl) * ET;
        __syncthreads();   // protect LDS vs previous tile's epilogue readers

        // ---- phase 1: meta + xj gather ----
        if (t < 16) {
            lds_dst[t] = edge_dst[e0 + t];
            lds_len[t] = edge_length[e0 + t];
            const float4v ea = *(const float4v*)(edge_attr + 4 * (e0 + t));
            lds_sh[t * 4 + 0] = ea[0]; lds_sh[t * 4 + 1] = ea[1];
            lds_sh[t * 4 + 2] = ea[2]; lds_sh[t * 4 + 3] = ea[3];
        }
        {
            const int e_loc = prog * 4 + quad;            // wave loads 4 edges
            const int src = edge_src[e0 + e_loc];
            const float4v xv = *(const float4v*)(x + src * 64 + qm * 4);
            *(float4v*)(&lds_xj[e_loc * 68 + qm * 4]) = xv;
        }
        __syncthreads();

        // ---- phase 2a: per-(e,u) coefficients ----
        {
            const int e = t & 15, u = t >> 4;
            const float s1x = lds_sh[e * 4 + 1];
            const float s1y = lds_sh[e * 4 + 2];
            const float s1z = lds_sh[e * 4 + 3];
            const float x0 = lds_xj[e * 68 + 16 + 3 * u];
            const float x1 = lds_xj[e * 68 + 17 + 3 * u];
            const float x2 = lds_xj[e * 68 + 18 + 3 * u];
            lds_b1[e * 68 + u] = fmaf(x0, s1x, fmaf(x1, s1y, x2 * s1z));
            lds_xt[(e * 3 + 0) * 20 + u] = x0;
            lds_xt[(e * 3 + 1) * 20 + u] = x1;
            lds_xt[(e * 3 + 2) * 20 + u] = x2;
        }
        // ---- phase 2b: h = silu(radial @ W1 / sqrt(8)) -> fp32 LDS ----
        {
            const int e = t & 15, c0 = (t >> 4) * 4;
            const float len = lds_len[e];
            float rad[8];
            #pragma unroll
            for (int r = 0; r < 8; ++r) {
                const float d = len - 0.7142857143f * (float)r;
                rad[r] = __expf(-0.5f * d * d);
            }
            float4v hv;
            #pragma unroll
            for (int i = 0; i < 4; ++i) {
                const float4v wA = *(const float4v*)(&lds_w1t[(c0 + i) * 8]);
                const float4v wB = *(const float4v*)(&lds_w1t[(c0 + i) * 8 + 4]);
                float s = rad[0] * wA[0] + rad[1] * wA[1] + rad[2] * wA[2] + rad[3] * wA[3]
                        + rad[4] * wB[0] + rad[5] * wB[1] + rad[6] * wB[2] + rad[7] * wB[3];
                s *= 0.3535533906f;
                hv[i] = s / (1.f + __expf(-s));
            }
            *(float4v*)(&lds_h[e * 72 + c0]) = hv;
        }
        __syncthreads();

        // ---- phase 3: build A fragments (f16 hi/lo from fp32 LDS) ----
        // A-frag: lane holds h[m=qm][k = kf*32 + quad*8 + j]
        const float* hrow = &lds_h[qm * 72];
        const float4v fa = *(const float4v*)(hrow + quad * 8);
        const float4v fb = *(const float4v*)(hrow + quad * 8 + 4);
        const float4v fc = *(const float4v*)(hrow + 32 + quad * 8);
        const float4v fd = *(const float4v*)(hrow + 32 + quad * 8 + 4);
        half8 ah0, al0, ah1, al1;
        #pragma unroll
        for (int j = 0; j < 4; ++j) {
            _Float16 hh;
            hh = (_Float16)fa[j]; ah0[j]     = hh; al0[j]     = (_Float16)(fa[j] - (float)hh);
            hh = (_Float16)fb[j]; ah0[4 + j] = hh; al0[4 + j] = (_Float16)(fb[j] - (float)hh);
            hh = (_Float16)fc[j]; ah1[j]     = hh; al1[j]     = (_Float16)(fc[j] - (float)hh);
            hh = (_Float16)fd[j]; ah1[4 + j] = hh; al1[4 + j] = (_Float16)(fd[j] - (float)hh);
        }
        // ---- MFMA (16 u-tiles, K=64, hi+lo A split) ----
        float4v acc[16];
        #pragma unroll
        for (int u = 0; u < 16; ++u) acc[u] = (float4v){0.f, 0.f, 0.f, 0.f};
        #pragma unroll
        for (int u = 0; u < 16; ++u) {
            acc[u] = __builtin_amdgcn_mfma_f32_16x16x32_f16(ah0, bfr[u][0], acc[u], 0, 0, 0);
            acc[u] = __builtin_amdgcn_mfma_f32_16x16x32_f16(al0, bfr[u][0], acc[u], 0, 0, 0);
            acc[u] = __builtin_amdgcn_mfma_f32_16x16x32_f16(ah1, bfr[u][1], acc[u], 0, 0, 0);
            acc[u] = __builtin_amdgcn_mfma_f32_16x16x32_f16(al1, bfr[u][1], acc[u], 0, 0, 0);
        }
        // C layout: col v = qm, row e = quad*4 + r  (r = reg)

        // ---- epilogue: u-contraction + DIRECT per-prog atomics ----
        if (prog == 0 || prog == 2) {
            #pragma unroll
            for (int r = 0; r < 4; ++r) {
                const int er = quad * 4 + r;
                const float4v* b = (const float4v*)&lds_xj[er * 68];   // xj0 rows
                float s = 0.f;
                #pragma unroll
                for (int c4 = 0; c4 < 4; ++c4) {
                    const float4v p = b[c4];
                    s = fmaf(p[0], acc[c4 * 4 + 0][r], s);
                    s = fmaf(p[1], acc[c4 * 4 + 1][r], s);
                    s = fmaf(p[2], acc[c4 * 4 + 2][r], s);
                    s = fmaf(p[3], acc[c4 * 4 + 3][r], s);
                }
                float* op = out + lds_dst[er] * 64;
                if (prog == 0) {
                    // m0 term 1: sum_u xj0*sh0 * w0[u,v]
                    atomicAdd(op + qm, s * lds_sh[er * 4]);
                } else {
                    // m1 term 1: (sum_u xj0*w2[u,v]) * sh1[k]
                    #pragma unroll
                    for (int k = 0; k < 3; ++k)
                        atomicAdd(op + 16 + qm * 3 + k, s * lds_sh[er * 4 + 1 + k]);
                }
            }
        } else if (prog == 1) {
            // m0 term 2: sum_u b1[u]*w1[u,v]  (INV_SQRT3 folded into bfr)
            #pragma unroll
            for (int r = 0; r < 4; ++r) {
                const int er = quad * 4 + r;
                const float4v* b = (const float4v*)&lds_b1[er * 68];
                float s = 0.f;
                #pragma unroll
                for (int c4 = 0; c4 < 4; ++c4) {
                    const float4v p = b[c4];
                    s = fmaf(p[0], acc[c4 * 4 + 0][r], s);
                    s = fmaf(p[1], acc[c4 * 4 + 1][r], s);
                    s = fmaf(p[2], acc[c4 * 4 + 2][r], s);
                    s = fmaf(p[3], acc[c4 * 4 + 3][r], s);
                }
                atomicAdd(out + lds_dst[er] * 64 + qm, s);
            }
        } else {
            // m1 term 2: sh0 * sum_u xj1[u,k]*w3[u,v]
            #pragma unroll
            for (int r = 0; r < 4; ++r) {
                const int er = quad * 4 + r;
                const float sh0 = lds_sh[er * 4];
                float* op = out + lds_dst[er] * 64;
                #pragma unroll
                for (int k = 0; k < 3; ++k) {
                    const float4v* b = (const float4v*)&lds_xt[(er * 3 + k) * 20];
                    float s = 0.f;
                    #pragma unroll
                    for (int c4 = 0; c4 < 4; ++c4) {
                        const float4v p = b[c4];
                        s = fmaf(p[0], acc[c4 * 4 + 0][r], s);
                        s = fmaf(p[1], acc[c4 * 4 + 1][r], s);
                        s = fmaf(p[2], acc[c4 * 4 + 2][r], s);
                        s = fmaf(p[3], acc[c4 * 4 + 3][r], s);
                    }
                    atomicAdd(op + 16 + qm * 3 + k, s * sh0);
                }
            }
        }
        // no barrier needed here: next-iteration top barrier orders epilogue
        // LDS reads before phase-1 overwrites
    }
}

extern "C" void kernel_launch(void* const* d_in, const int* in_sizes, int n_in,
                              void* d_out, int out_size, void* d_ws, size_t ws_size,
                              hipStream_t stream) {
    const float* x           = (const float*)d_in[0];
    const float* edge_attr   = (const float*)d_in[1];
    const float* edge_length = (const float*)d_in[2];
    const int*   edge_src    = (const int*)d_in[3];
    const int*   edge_dst    = (const int*)d_in[4];
    const float* W1          = (const float*)d_in[5];
    const float* W2          = (const float*)d_in[6];
    const float* L0          = (const float*)d_in[7];
    const float* L1          = (const float*)d_in[8];
    float* out = (float*)d_out;

    sc_kernel<<<(N_NODES * 64 + 255) / 256, 256, 0, stream>>>(x, L0, L1, out);
    edge_kernel<<<NBLK, 256, 0, stream>>>(
        x, edge_attr, edge_length, edge_src, edge_dst, W1, W2, out);
}